// Round 14
// baseline (64.227 us; speedup 1.0000x reference)
//
#include <hip/hip_runtime.h>
#include <hip/hip_bf16.h>

// SimpleDIN v14 — v13 with the bias-MFMA inputs (WD frags + att_b1) loaded
// from GLOBAL before the barrier (off the critical path). LDS stages only
// G|C (20 KB, v11 size). Main loop body = v11 (known-good, no spill).

typedef __attribute__((ext_vector_type(8))) short          bf16x8;
typedef __attribute__((ext_vector_type(8))) unsigned short u16x8;
typedef __attribute__((ext_vector_type(4))) float          f32x4;

__device__ __forceinline__ int swz_gran(int row, int g) {
    return row * 64 + ((g ^ (row & 7)) << 3);      // u16 index of 16B granule
}
__device__ __forceinline__ int swz_elem(int row, int col) {
    return row * 64 + (((col >> 3) ^ (row & 7)) << 3) + (col & 7);
}

// ---------------- Kernel P: pack only (grid 40) ----------------
extern "C" __global__ __launch_bounds__(256)
void din_prep(const float* __restrict__ att_w1,
              __hip_bfloat16* __restrict__ gcb)   // [15360] G|C|WD swizzled
{
    const int i = blockIdx.x * 256 + threadIdx.x;
    if (i < 64 * 80) {
        const int d = i / 80;
        const int j = i - d * 80;
        const float wa = att_w1[d * 80 + j];
        const float wb = att_w1[(64 + d) * 80 + j];
        const float wc = att_w1[(128 + d) * 80 + j];
        const float wd = att_w1[(192 + d) * 80 + j];
        const int sw = swz_elem(j, d);
        gcb[sw]         = __float2bfloat16(wa + wd);   // G
        gcb[5120 + sw]  = __float2bfloat16(wc);        // C
        gcb[10240 + sw] = __float2bfloat16(wb - wd);   // WD
    }
}

// ---------------- Kernel M: main (grid 1024, 4 b per block) ----------------
struct __align__(16) LdsW {
    unsigned short gcb[10240];    // 20480 B: G | C
    float w2[80];                 // 320
    float wsc[4][208];            // 3328 per-wave logit exchange
    float aux[4][128];            // 2048
    float h1s[4][64];             // 1024
};                                 // 27200 B -> 4 blocks/CU (grid-limited)

extern "C" __global__ __launch_bounds__(256, 4)
void din_main(const int* __restrict__ user_ids,
              const int* __restrict__ item_ids,
              const int* __restrict__ seq,
              const float* __restrict__ user_table,
              const float* __restrict__ item_table,
              const float* __restrict__ att_b1,
              const float* __restrict__ att_w2,
              const float* __restrict__ pred_w1,
              const float* __restrict__ pred_b1,
              const float* __restrict__ pred_w2,
              const float* __restrict__ pred_b2,
              const float* __restrict__ pred_w3,
              const float* __restrict__ pred_b3,
              const unsigned short* __restrict__ gcb_g,
              float* __restrict__ out)
{
    __shared__ LdsW L;
    const int t  = threadIdx.x;
    const int wv = t >> 6;                  // wave = one batch element
    const int l  = t & 63;
    const int lr = l & 15;
    const int ks = l >> 4;
    const int b  = blockIdx.x * 4 + wv;

    // stage G|C into LDS (only barrier-protected data)
    {
        const u16x8* src = reinterpret_cast<const u16x8*>(gcb_g);
        u16x8* dst = reinterpret_cast<u16x8*>(L.gcb);
        #pragma unroll
        for (int i = 0; i < 5; ++i) dst[t + i * 256] = src[t + i * 256];
    }
    if (t < 80) L.w2[t] = att_w2[t];

    // per-lane tgt slices (k = 8ks..8ks+7 and 32+8ks..32+8ks+7)
    const int iid = item_ids[b];
    const float4* tp = reinterpret_cast<const float4*>(
        item_table + (size_t)iid * 64);
    const float4 tg0 = tp[2 * ks], tg1 = tp[2 * ks + 1];
    const float4 tg2 = tp[8 + 2 * ks], tg3 = tp[8 + 2 * ks + 1];
    const int uid = user_ids[b];
    const float uem = user_table[(size_t)uid * 64 + l];
    const int* seqb = seq + b * 200;

    // WD frags + b1 from GLOBAL, pre-barrier (L2-hot; overlaps everything)
    bf16x8 wdr0[5], wdr1[5];
    float b1_r[5];
    #pragma unroll
    for (int nt = 0; nt < 5; ++nt) {
        const int j = nt * 16 + lr;
        wdr0[nt] = *reinterpret_cast<const bf16x8*>(
            &gcb_g[10240 + swz_gran(j, ks)]);
        wdr1[nt] = *reinterpret_cast<const bf16x8*>(
            &gcb_g[10240 + swz_gran(j, 4 + ks)]);
        b1_r[nt] = att_b1[j];
    }

    __syncthreads();                        // gcb/w2 ready

    // ---- bias_eff via broadcast-A MFMA (pure register work now) ----
    float bias_r[5], w2_r[5];
    {
        union { u16x8 u; bf16x8 bf; __hip_bfloat162 h2[4]; } T0, T1;
        T0.h2[0] = __float22bfloat162_rn(float2{tg0.x, tg0.y});
        T0.h2[1] = __float22bfloat162_rn(float2{tg0.z, tg0.w});
        T0.h2[2] = __float22bfloat162_rn(float2{tg1.x, tg1.y});
        T0.h2[3] = __float22bfloat162_rn(float2{tg1.z, tg1.w});
        T1.h2[0] = __float22bfloat162_rn(float2{tg2.x, tg2.y});
        T1.h2[1] = __float22bfloat162_rn(float2{tg2.z, tg2.w});
        T1.h2[2] = __float22bfloat162_rn(float2{tg3.x, tg3.y});
        T1.h2[3] = __float22bfloat162_rn(float2{tg3.z, tg3.w});
        #pragma unroll
        for (int nt = 0; nt < 5; ++nt) {
            f32x4 bacc = (f32x4){0.f, 0.f, 0.f, 0.f};
            bacc = __builtin_amdgcn_mfma_f32_16x16x32_bf16(T0.bf, wdr0[nt], bacc, 0, 0, 0);
            bacc = __builtin_amdgcn_mfma_f32_16x16x32_bf16(T1.bf, wdr1[nt], bacc, 0, 0, 0);
            bias_r[nt] = bacc[0] + b1_r[nt];    // all C rows equal
            w2_r[nt]   = L.w2[nt * 16 + lr];
        }
    }

    // ---- fused loop: 13 M-tiles, logits + online softmax-pooling ----
    float pl[8], ph[8];
    #pragma unroll
    for (int e = 0; e < 8; ++e) { pl[e] = 0.f; ph[e] = 0.f; }
    float mrun = -1e30f, ssum = 0.f;

    for (int mt = 0; mt < 13; ++mt) {
        const int srow = mt * 16 + lr;
        const bool val = srow < 200;
        const int row = val ? seqb[srow] : 0;
        const float4* rp = reinterpret_cast<const float4*>(
            item_table + (size_t)row * 64);
        float4 q0 = rp[2 * ks], q1 = rp[2 * ks + 1];
        float4 q2 = rp[8 + 2 * ks], q3 = rp[8 + 2 * ks + 1];
        if (!val) {
            q0 = make_float4(0.f, 0.f, 0.f, 0.f);
            q1 = make_float4(0.f, 0.f, 0.f, 0.f);
            q2 = make_float4(0.f, 0.f, 0.f, 0.f);
            q3 = make_float4(0.f, 0.f, 0.f, 0.f);
        }
        union { u16x8 u; bf16x8 bf; __hip_bfloat162 h2[4]; } A0, A1, A2, A3;
        A0.h2[0] = __float22bfloat162_rn(float2{q0.x, q0.y});
        A0.h2[1] = __float22bfloat162_rn(float2{q0.z, q0.w});
        A0.h2[2] = __float22bfloat162_rn(float2{q1.x, q1.y});
        A0.h2[3] = __float22bfloat162_rn(float2{q1.z, q1.w});
        A1.h2[0] = __float22bfloat162_rn(float2{q2.x, q2.y});
        A1.h2[1] = __float22bfloat162_rn(float2{q2.z, q2.w});
        A1.h2[2] = __float22bfloat162_rn(float2{q3.x, q3.y});
        A1.h2[3] = __float22bfloat162_rn(float2{q3.z, q3.w});
        A2.h2[0] = __float22bfloat162_rn(float2{q0.x * tg0.x, q0.y * tg0.y});
        A2.h2[1] = __float22bfloat162_rn(float2{q0.z * tg0.z, q0.w * tg0.w});
        A2.h2[2] = __float22bfloat162_rn(float2{q1.x * tg1.x, q1.y * tg1.y});
        A2.h2[3] = __float22bfloat162_rn(float2{q1.z * tg1.z, q1.w * tg1.w});
        A3.h2[0] = __float22bfloat162_rn(float2{q2.x * tg2.x, q2.y * tg2.y});
        A3.h2[1] = __float22bfloat162_rn(float2{q2.z * tg2.z, q2.w * tg2.w});
        A3.h2[2] = __float22bfloat162_rn(float2{q3.x * tg3.x, q3.y * tg3.y});
        A3.h2[3] = __float22bfloat162_rn(float2{q3.z * tg3.z, q3.w * tg3.w});

        f32x4 acc[5];
        #pragma unroll
        for (int nt = 0; nt < 5; ++nt)
            acc[nt] = (f32x4){0.f, 0.f, 0.f, 0.f};
        #pragma unroll
        for (int nt = 0; nt < 5; ++nt) {
            const int j = nt * 16 + lr;
            const bf16x8 g0 = *reinterpret_cast<const bf16x8*>(
                &L.gcb[swz_gran(j, ks)]);
            const bf16x8 g1 = *reinterpret_cast<const bf16x8*>(
                &L.gcb[swz_gran(j, 4 + ks)]);
            const bf16x8 c0 = *reinterpret_cast<const bf16x8*>(
                &L.gcb[5120 + swz_gran(j, ks)]);
            const bf16x8 c1 = *reinterpret_cast<const bf16x8*>(
                &L.gcb[5120 + swz_gran(j, 4 + ks)]);
            acc[nt] = __builtin_amdgcn_mfma_f32_16x16x32_bf16(A0.bf, g0, acc[nt], 0, 0, 0);
            acc[nt] = __builtin_amdgcn_mfma_f32_16x16x32_bf16(A1.bf, g1, acc[nt], 0, 0, 0);
            acc[nt] = __builtin_amdgcn_mfma_f32_16x16x32_bf16(A2.bf, c0, acc[nt], 0, 0, 0);
            acc[nt] = __builtin_amdgcn_mfma_f32_16x16x32_bf16(A3.bf, c1, acc[nt], 0, 0, 0);
        }

        // logits; invalid rows -> -1e30
        float pv[4];
        #pragma unroll
        for (int r = 0; r < 4; ++r) {
            const int s = mt * 16 + ks * 4 + r;
            float p = 0.f;
            #pragma unroll
            for (int nt = 0; nt < 5; ++nt)
                p += fmaxf(acc[nt][r] + bias_r[nt], 0.f) * w2_r[nt];
            p += __shfl_xor(p, 1);
            p += __shfl_xor(p, 2);
            p += __shfl_xor(p, 4);
            p += __shfl_xor(p, 8);
            if (s >= 200) p = -1e30f;
            pv[r] = p;
            if (lr == 0 && s < 200) L.wsc[wv][s] = p;
        }
        float tmax = fmaxf(fmaxf(pv[0], pv[1]), fmaxf(pv[2], pv[3]));
        tmax = fmaxf(tmax, __shfl_xor(tmax, 16));
        tmax = fmaxf(tmax, __shfl_xor(tmax, 32));
        if (tmax > mrun) {
            const float sc = __expf(mrun - tmax);
            #pragma unroll
            for (int e = 0; e < 8; ++e) { pl[e] *= sc; ph[e] *= sc; }
            ssum *= sc;
            mrun = tmax;
        }
        float w = 0.f;
        if (val) w = __expf(L.wsc[wv][srow] - mrun);
        ssum += w;
        pl[0] = fmaf(w, q0.x, pl[0]); pl[1] = fmaf(w, q0.y, pl[1]);
        pl[2] = fmaf(w, q0.z, pl[2]); pl[3] = fmaf(w, q0.w, pl[3]);
        pl[4] = fmaf(w, q1.x, pl[4]); pl[5] = fmaf(w, q1.y, pl[5]);
        pl[6] = fmaf(w, q1.z, pl[6]); pl[7] = fmaf(w, q1.w, pl[7]);
        ph[0] = fmaf(w, q2.x, ph[0]); ph[1] = fmaf(w, q2.y, ph[1]);
        ph[2] = fmaf(w, q2.z, ph[2]); ph[3] = fmaf(w, q2.w, ph[3]);
        ph[4] = fmaf(w, q3.x, ph[4]); ph[5] = fmaf(w, q3.y, ph[5]);
        ph[6] = fmaf(w, q3.z, ph[6]); ph[7] = fmaf(w, q3.w, ph[7]);
    }

    // ---- reduce over lr (16 lanes) ----
    #pragma unroll
    for (int msk = 1; msk < 16; msk <<= 1) {
        #pragma unroll
        for (int e = 0; e < 8; ++e) {
            pl[e] += __shfl_xor(pl[e], msk);
            ph[e] += __shfl_xor(ph[e], msk);
        }
        ssum += __shfl_xor(ssum, msk);
    }
    const float inv = 1.f / ssum;
    if (lr == 0) {
        #pragma unroll
        for (int e = 0; e < 8; ++e) {
            L.aux[wv][64 + 8 * ks + e]      = pl[e] * inv;
            L.aux[wv][64 + 32 + 8 * ks + e] = ph[e] * inv;
        }
    }
    L.aux[wv][l] = uem;

    // ---- per-wave MLP 128 -> 64 -> 32 -> 1 ----
    float a0 = pred_b1[l], a1 = 0.f, a2 = 0.f, a3 = 0.f;
    #pragma unroll 4
    for (int k = 0; k < 128; k += 4) {
        a0 = fmaf(L.aux[wv][k],     pred_w1[k * 64 + l],       a0);
        a1 = fmaf(L.aux[wv][k + 1], pred_w1[(k + 1) * 64 + l], a1);
        a2 = fmaf(L.aux[wv][k + 2], pred_w1[(k + 2) * 64 + l], a2);
        a3 = fmaf(L.aux[wv][k + 3], pred_w1[(k + 3) * 64 + l], a3);
    }
    L.h1s[wv][l] = fmaxf((a0 + a1) + (a2 + a3), 0.f);
    const int j2 = l & 31;
    float c0 = pred_b2[j2], c1 = 0.f;
    #pragma unroll 4
    for (int k = 0; k < 64; k += 2) {
        c0 = fmaf(L.h1s[wv][k],     pred_w2[k * 32 + j2],       c0);
        c1 = fmaf(L.h1s[wv][k + 1], pred_w2[(k + 1) * 32 + j2], c1);
    }
    float p = fmaxf(c0 + c1, 0.f) * pred_w3[j2];
    p += __shfl_xor(p, 1);
    p += __shfl_xor(p, 2);
    p += __shfl_xor(p, 4);
    p += __shfl_xor(p, 8);
    p += __shfl_xor(p, 16);
    if (l == 0) {
        const float z = p + pred_b3[0];
        out[b] = 1.f / (1.f + __expf(-z));
    }
}

extern "C" void kernel_launch(void* const* d_in, const int* in_sizes, int n_in,
                              void* d_out, int out_size, void* d_ws, size_t ws_size,
                              hipStream_t stream)
{
    const int*   user_ids   = (const int*)  d_in[0];
    const int*   item_ids   = (const int*)  d_in[1];
    const int*   seq        = (const int*)  d_in[2];
    const float* user_table = (const float*)d_in[3];
    const float* item_table = (const float*)d_in[4];
    const float* att_w1     = (const float*)d_in[5];
    const float* att_b1     = (const float*)d_in[6];
    const float* att_w2     = (const float*)d_in[7];
    // d_in[8] = att_b2: cancels in softmax, unused
    const float* pred_w1    = (const float*)d_in[9];
    const float* pred_b1    = (const float*)d_in[10];
    const float* pred_w2    = (const float*)d_in[11];
    const float* pred_b2    = (const float*)d_in[12];
    const float* pred_w3    = (const float*)d_in[13];
    const float* pred_b3    = (const float*)d_in[14];
    float* out = (float*)d_out;

    __hip_bfloat16* gcb = (__hip_bfloat16*)d_ws;               // 30720 B

    din_prep<<<40, 256, 0, stream>>>(att_w1, gcb);
    din_main<<<1024, 256, 0, stream>>>(user_ids, item_ids, seq,
                                       user_table, item_table,
                                       att_b1, att_w2,
                                       pred_w1, pred_b1, pred_w2, pred_b2,
                                       pred_w3, pred_b3,
                                       (const unsigned short*)gcb,
                                       out);
}